// Round 3
// baseline (7360.029 us; speedup 1.0000x reference)
//
#include <hip/hip_runtime.h>

// SpikeTimeSeriesForecaster: 3-layer LIF SNN, T=50, rate decode over last 10.
// FLOAT32 implementation intended to be bit-identical to a numpy float32
// replay of the reference (the harness's ref=np recomputation):
//  - x@W1: k-ascending single-accumulator FMA chain (== sgemm micro-kernel).
//  - s@W2 / s@W3: s in {0,1} => products exact => masked fp32 add in k-order.
//  - LIF update 0.9f*V + I via __fmul_rn/__fadd_rn (separately rounded,
//    non-contractible — numpy does two ufuncs, no FMA).
//  - biases are all zeros; added after the k-sum like numpy (no-op here).
//
// One persistent block owns BB=32 batch rows for all 50 timesteps; V/r state
// lives in registers; spikes are exchanged via LDS bitmasks (bit b = row b).

#define B_TOT  8192
#define IN     256
#define H1     512
#define H2     256
#define NOUT   64
#define T_STEPS 50
#define WIN    10
#define BB     32
#define NTHR   512

// masked fp32 addend: w if bit `bit` of m is set, else +0.0f (bfe.i32 + and)
__device__ __forceinline__ float maskf(float w, unsigned m, int bit) {
    int msk = (int)(m << (31 - bit)) >> 31;        // 0 or -1
    return __uint_as_float(__float_as_uint(w) & (unsigned)msk);
}

// numpy LIF membrane update: t = rn(0.9f*V); V' = rn(t + I). No contraction.
__device__ __forceinline__ float lif_v(float V, float I) {
    return __fadd_rn(__fmul_rn(0.9f, V), I);
}

__global__ __launch_bounds__(NTHR, 2)
void snn_lif_fp32(const float* __restrict__ x,
                  const float* __restrict__ W1, const float* __restrict__ b1,
                  const float* __restrict__ W2, const float* __restrict__ b2,
                  const float* __restrict__ W3, const float* __restrict__ b3,
                  float* __restrict__ out)
{
    __shared__ float    xs[BB * IN];       // 32 KiB: staged x rows
    __shared__ unsigned s1b[H1];           // 2 KiB: layer-1 spikes, bit b per h1
    __shared__ unsigned s2w_[H2];          // 1 KiB: layer-2 spikes, 32 b-bits per h2

    const int t  = threadIdx.x;            // 512 threads
    const int b0 = blockIdx.x * BB;

    // ---- stage x rows ----
    for (int i = t; i < BB * IN; i += NTHR) xs[i] = x[(size_t)b0 * IN + i];
    __syncthreads();

    // ---- phase 0: I1[b][h1=t] = fma-chain_k(x[b,k]*W1[k,t]) + b1[t], fp32 ----
    float I1r[BB];
    #pragma unroll
    for (int b = 0; b < BB; b++) I1r[b] = 0.0f;
    for (int k = 0; k < IN; k++) {
        float w = W1[k * H1 + t];
        #pragma unroll
        for (int b = 0; b < BB; b++)
            I1r[b] = __fmaf_rn(xs[b * IN + k], w, I1r[b]);  // sgemm FMA order
    }
    {
        float bb = b1[t];
        #pragma unroll
        for (int b = 0; b < BB; b++) I1r[b] = __fadd_rn(I1r[b], bb);
    }

    // ---- per-thread state ----
    float V1[BB];
    #pragma unroll
    for (int b = 0; b < BB; b++) V1[b] = 0.0f;
    unsigned r1 = 0;

    const int jj = t & (H2 - 1);   // layer-2 column
    const int q  = t >> 8;         // which 16-row half (rows q*16..q*16+15)
    float V2[16];
    #pragma unroll
    for (int i = 0; i < 16; i++) V2[i] = 0.0f;
    unsigned r2 = 0;
    const float b2v = b2[jj];

    const int o    = t & (NOUT - 1);   // layer-3 column
    const int brow = (t >> 6) & 7;     // rows brow + 8*i, i=0..3
    float V3[4];
    #pragma unroll
    for (int i = 0; i < 4; i++) V3[i] = 0.0f;
    unsigned r3 = 0;
    int cnt[4] = {0, 0, 0, 0};
    const float b3v = b3[o];

    const float* w2p = W2 + jj;
    const float* w3p = W3 + o;

    // ---- time loop ----
    for (int step = 0; step < T_STEPS; step++) {
        // layer 1 (h1 = t owns all 32 batch rows). r bit = fired last step.
        unsigned bits1 = 0;
        #pragma unroll
        for (int b = 0; b < BB; b++) {
            float V = lif_v(V1[b], I1r[b]);
            bool fire = (V >= 1.0f) & !((r1 >> b) & 1u);
            V1[b] = fire ? 0.0f : V;
            bits1 |= (unsigned)fire << b;
        }
        s1b[t] = bits1;
        r1 = bits1;
        __syncthreads();

        // layer 2: I2[b, jj] for b in [q*16, q*16+16): k-ordered sum, then +b2
        float acc[16];
        #pragma unroll
        for (int i = 0; i < 16; i++) acc[i] = 0.0f;
        for (int k = 0; k < H1; k++) {
            unsigned m = s1b[k] >> (q * 16);          // wave-uniform broadcast
            float w = w2p[(size_t)k * H2];            // W2[k*256 + jj]
            #pragma unroll
            for (int i = 0; i < 16; i++)
                acc[i] = __fadd_rn(acc[i], maskf(w, m, i));  // == fma(s,w,acc)
        }
        unsigned bits2 = 0;
        #pragma unroll
        for (int i = 0; i < 16; i++) {
            float I2 = __fadd_rn(acc[i], b2v);        // bias last (b2 == 0)
            float V = lif_v(V2[i], I2);
            bool fire = (V >= 1.0f) & !((r2 >> i) & 1u);
            V2[i] = fire ? 0.0f : V;
            bits2 |= (unsigned)fire << i;
        }
        ((unsigned short*)s2w_)[jj * 2 + q] = (unsigned short)bits2;
        r2 = bits2;
        __syncthreads();

        // layer 3: I3[b, o] for b = brow + 8*i: k-ordered sum, then +b3
        float acc3[4];
        #pragma unroll
        for (int i = 0; i < 4; i++) acc3[i] = 0.0f;
        for (int k = 0; k < H2; k++) {
            unsigned m = s2w_[k];
            float w = w3p[(size_t)k * NOUT];
            #pragma unroll
            for (int i = 0; i < 4; i++)
                acc3[i] = __fadd_rn(acc3[i], maskf(w, m, brow + 8 * i));
        }
        #pragma unroll
        for (int i = 0; i < 4; i++) {
            float I3 = __fadd_rn(acc3[i], b3v);
            float V = lif_v(V3[i], I3);
            bool fire = (V >= 1.0f) & !((r3 >> i) & 1u);
            V3[i] = fire ? 0.0f : V;
            r3 = (r3 & ~(1u << i)) | ((unsigned)fire << i);
            if (step >= T_STEPS - WIN) cnt[i] += (int)fire;
        }
        // next s1b / s2w_ writes are fenced by the first sync of the next step
    }

    // ---- output: mean over last WIN steps (fp32 division, like np) ----
    #pragma unroll
    for (int i = 0; i < 4; i++) {
        int b = brow + 8 * i;
        out[(size_t)(b0 + b) * NOUT + o] = (float)cnt[i] / 10.0f;
    }
}

extern "C" void kernel_launch(void* const* d_in, const int* in_sizes, int n_in,
                              void* d_out, int out_size, void* d_ws, size_t ws_size,
                              hipStream_t stream)
{
    const float* x  = (const float*)d_in[0];
    const float* W1 = (const float*)d_in[1];
    const float* b1 = (const float*)d_in[2];
    const float* W2 = (const float*)d_in[3];
    const float* b2 = (const float*)d_in[4];
    const float* W3 = (const float*)d_in[5];
    const float* b3 = (const float*)d_in[6];
    float* out = (float*)d_out;

    dim3 grid(B_TOT / BB);   // 256 blocks
    dim3 block(NTHR);        // 512 threads = 8 waves
    hipLaunchKernelGGL(snn_lif_fp32, grid, block, 0, stream,
                       x, W1, b1, W2, b2, W3, b3, out);
}

// Round 4
// 2285.885 us; speedup vs baseline: 3.2198x; 3.2198x over previous
//
#include <hip/hip_runtime.h>

// SpikeTimeSeriesForecaster: 3-layer LIF SNN, T=50, rate decode over last 10.
// Bit-exact fp32 (proven round 3: absmax 0.0). This round: performance.
//  - Spikes expanded ONCE by their producer into fp32 {0,1} arrays in LDS;
//    consumers read via broadcast ds_read_b128 (no per-use mask ALU).
//  - s@W accumulated with v_pk_fma_f32 (2 MACs/inst). fma(w, s, acc) with
//    s in {0.0f,1.0f} is bit-identical to sgemm's fma(s,w,acc): product is
//    exactly w or +/-0 (same sign as s*w), k-order unchanged.
//  - BB=16 rows/block, 512 blocks x 512 thr -> 2 blocks/CU, 16 waves/CU.

typedef float f32x2 __attribute__((ext_vector_type(2)));
typedef float f32x4 __attribute__((ext_vector_type(4)));

#define B_TOT  8192
#define IN     256
#define H1     512
#define H2     256
#define NOUT   64
#define T_STEPS 50
#define WIN    10
#define BB     16
#define NTHR   512

// acc = a*b + acc, packed 2x fp32, IEEE rn per half (bit-exact to 2 scalar fmas)
__device__ __forceinline__ void pk_fma(f32x2& acc, f32x2 a, f32x2 b) {
    asm("v_pk_fma_f32 %0, %1, %2, %0" : "+v"(acc) : "v"(a), "v"(b));
}

// numpy LIF membrane update: rn(0.9f*V) then rn(t+I); no FMA contraction.
__device__ __forceinline__ float lif_v(float V, float I) {
    return __fadd_rn(__fmul_rn(0.9f, V), I);
}

__global__ __launch_bounds__(NTHR, 4)
void snn_lif_fp32_pk(const float* __restrict__ x,
                     const float* __restrict__ W1, const float* __restrict__ b1,
                     const float* __restrict__ W2, const float* __restrict__ b2,
                     const float* __restrict__ W3, const float* __restrict__ b3,
                     float* __restrict__ out)
{
    // S1f: layer-1 spike floats [h1][b] (32 KiB); doubles as xs[BB][IN] in phase 0.
    __shared__ __align__(16) float S1f[H1 * BB];
    // S2f: layer-2 spike floats [h2][b] (16 KiB).
    __shared__ __align__(16) float S2f[H2 * BB];

    const int t  = threadIdx.x;            // 0..511
    const int b0 = blockIdx.x * BB;

    // ---- phase 0: stage x, compute I1[b][h1=t] via k-ascending fma chain ----
    float* xs = S1f;                       // [BB][IN], dead after phase 0
    for (int i = t; i < BB * IN; i += NTHR) xs[i] = x[(size_t)b0 * IN + i];
    __syncthreads();

    float I1r[BB];
    #pragma unroll
    for (int b = 0; b < BB; b++) I1r[b] = 0.0f;
    for (int k = 0; k < IN; k++) {
        float w = W1[k * H1 + t];          // coalesced; xs reads are lane-uniform
        #pragma unroll
        for (int b = 0; b < BB; b++)
            I1r[b] = __fmaf_rn(xs[b * IN + k], w, I1r[b]);   // sgemm FMA order
    }
    {
        float bb = b1[t];
        #pragma unroll
        for (int b = 0; b < BB; b++) I1r[b] = __fadd_rn(I1r[b], bb);
    }
    __syncthreads();                       // xs dead; S1f is now the spike array

    // ---- per-thread state ----
    float V1[BB];                          // layer 1: h1 = t, all 16 rows
    #pragma unroll
    for (int b = 0; b < BB; b++) V1[b] = 0.0f;
    unsigned r1 = 0;

    const int jj = t & (H2 - 1);           // layer-2 column
    const int h  = t >> 8;                 // 0/1: rows h*8 .. h*8+7
    float V2[8];
    #pragma unroll
    for (int i = 0; i < 8; i++) V2[i] = 0.0f;
    unsigned r2 = 0;
    const float b2v = b2[jj];
    const float* w2c = W2 + jj;

    const int o  = t & (NOUT - 1);         // layer-3 column
    const int bp = t >> 6;                 // 0..7: rows 2bp, 2bp+1 (wave-uniform)
    float V3[2] = {0.0f, 0.0f};
    unsigned r3 = 0;
    int cnt[2] = {0, 0};
    const float b3v = b3[o];
    const float* w3c = W3 + o;

    // ---- time loop: 2 barriers per step ----
    for (int step = 0; step < T_STEPS; step++) {
        // layer 1: update 16 rows, expand spikes to floats, write S1f[t][0..15]
        float sf[BB];
        unsigned nr1 = 0;
        #pragma unroll
        for (int b = 0; b < BB; b++) {
            float V = lif_v(V1[b], I1r[b]);
            bool act = (V >= 1.0f) & !((r1 >> b) & 1u);
            V1[b] = act ? 0.0f : V;
            sf[b] = act ? 1.0f : 0.0f;
            nr1 |= (unsigned)act << b;
        }
        r1 = nr1;
        {
            f32x4* dst = (f32x4*)(S1f + t * BB);
            #pragma unroll
            for (int j = 0; j < 4; j++)
                dst[j] = (f32x4){sf[4*j], sf[4*j+1], sf[4*j+2], sf[4*j+3]};
        }
        __syncthreads();   // (A) S1f ready; also fences prev-step S2f readers

        // layer 2: 8 accs (b = h*8+0..7) x column jj.
        // per k: 1 coalesced w load + 2 broadcast ds_read_b128 + 4 v_pk_fma_f32
        f32x2 acc[4];
        #pragma unroll
        for (int p = 0; p < 4; p++) acc[p] = (f32x2){0.0f, 0.0f};
        const float* srow = S1f + h * 8;
        #pragma unroll 4
        for (int k = 0; k < H1; k++) {
            float w = w2c[(size_t)k * H2];
            f32x2 ws = {w, w};
            f32x4 sA = *(const f32x4*)(srow + k * BB);
            f32x4 sB = *(const f32x4*)(srow + k * BB + 4);
            pk_fma(acc[0], ws, __builtin_shufflevector(sA, sA, 0, 1));
            pk_fma(acc[1], ws, __builtin_shufflevector(sA, sA, 2, 3));
            pk_fma(acc[2], ws, __builtin_shufflevector(sB, sB, 0, 1));
            pk_fma(acc[3], ws, __builtin_shufflevector(sB, sB, 2, 3));
        }
        float sf2[8];
        unsigned nr2 = 0;
        #pragma unroll
        for (int i = 0; i < 8; i++) {
            float I2 = __fadd_rn(acc[i >> 1][i & 1], b2v);   // bias last
            float V = lif_v(V2[i], I2);
            bool act = (V >= 1.0f) & !((r2 >> i) & 1u);
            V2[i] = act ? 0.0f : V;
            sf2[i] = act ? 1.0f : 0.0f;
            nr2 |= (unsigned)act << i;
        }
        r2 = nr2;
        {
            f32x4* dst = (f32x4*)(S2f + jj * BB + h * 8);
            dst[0] = (f32x4){sf2[0], sf2[1], sf2[2], sf2[3]};
            dst[1] = (f32x4){sf2[4], sf2[5], sf2[6], sf2[7]};
        }
        __syncthreads();   // (B) S2f ready; also fences this-step S1f readers

        // layer 3: acc pair (b = 2bp, 2bp+1) x column o.
        // per k: 1 coalesced w load + 1 broadcast ds_read_b64 + 1 v_pk_fma_f32
        f32x2 a3 = {0.0f, 0.0f};
        const float* srow2 = S2f + bp * 2;
        #pragma unroll 4
        for (int k = 0; k < H2; k++) {
            float w = w3c[(size_t)k * NOUT];
            f32x2 ws = {w, w};
            f32x2 s = *(const f32x2*)(srow2 + k * BB);
            pk_fma(a3, ws, s);
        }
        #pragma unroll
        for (int e = 0; e < 2; e++) {
            float I3 = __fadd_rn(a3[e], b3v);
            float V = lif_v(V3[e], I3);
            bool act = (V >= 1.0f) & !((r3 >> e) & 1u);
            V3[e] = act ? 0.0f : V;
            r3 = (r3 & ~(1u << e)) | ((unsigned)act << e);
            if (step >= T_STEPS - WIN) cnt[e] += (int)act;
        }
        // next-step S1f writes are fenced by (B); next-step S2f writes by next (A)
    }

    // ---- output ----
    #pragma unroll
    for (int e = 0; e < 2; e++)
        out[(size_t)(b0 + 2 * bp + e) * NOUT + o] = (float)cnt[e] / 10.0f;
}

extern "C" void kernel_launch(void* const* d_in, const int* in_sizes, int n_in,
                              void* d_out, int out_size, void* d_ws, size_t ws_size,
                              hipStream_t stream)
{
    const float* x  = (const float*)d_in[0];
    const float* W1 = (const float*)d_in[1];
    const float* b1 = (const float*)d_in[2];
    const float* W2 = (const float*)d_in[3];
    const float* b2 = (const float*)d_in[4];
    const float* W3 = (const float*)d_in[5];
    const float* b3 = (const float*)d_in[6];
    float* out = (float*)d_out;

    dim3 grid(B_TOT / BB);   // 512 blocks -> 2 blocks/CU
    dim3 block(NTHR);        // 512 threads = 8 waves
    hipLaunchKernelGGL(snn_lif_fp32_pk, grid, block, 0, stream,
                       x, W1, b1, W2, b2, W3, b3, out);
}